// Round 1
// baseline (265.995 us; speedup 1.0000x reference)
//
#include <hip/hip_runtime.h>

#define SEQd 64
#define BATCHd 256
#define DF 40   // per-token feature dim == D_W

// ---------------------------------------------------------------------------
// 8-qubit statevector, one wave (64 lanes) per circuit.
// Amplitude flat index i (0..255): wire j <-> bit (7-j).
// Layout: i = lane*4 + r  => bits[1:0] = register index r, bits[7:2] = lane.
// ---------------------------------------------------------------------------

__device__ __forceinline__ float wave_sum(float v) {
#pragma unroll
  for (int m = 1; m < 64; m <<= 1) v += __shfl_xor(v, m, 64);
  return v;
}

// Single-qubit gate on amplitude-bit p. isRX: U=[[c,-is],[-is,c]], else RY=[[c,-s],[s,c]].
__device__ __forceinline__ void sq_gate(float ar[4], float ai[4], int p,
                                        float c, float s, bool isRX, int lane)
{
  if (p >= 2) {
    const int m = 1 << (p - 2);
    const int bit = (lane >> (p - 2)) & 1;
    const float t = bit ? s : -s;   // RY partner sign
#pragma unroll
    for (int r = 0; r < 4; ++r) {
      float br = __shfl_xor(ar[r], m, 64);
      float bi = __shfl_xor(ai[r], m, 64);
      float nr, ni;
      if (isRX) { nr = c * ar[r] + s * bi;  ni = c * ai[r] - s * br; }   // symmetric both sides
      else      { nr = c * ar[r] + t * br;  ni = c * ai[r] + t * bi; }
      ar[r] = nr; ai[r] = ni;
    }
  } else {
    const int step = 1 << p;
#pragma unroll
    for (int r0 = 0; r0 < 4; ++r0) {
      if (r0 & step) continue;
      const int r1 = r0 | step;
      const float a0r = ar[r0], a0i = ai[r0], a1r = ar[r1], a1i = ai[r1];
      if (isRX) {
        ar[r0] = c * a0r + s * a1i;  ai[r0] = c * a0i - s * a1r;
        ar[r1] = c * a1r + s * a0i;  ai[r1] = c * a1i - s * a0r;
      } else {
        ar[r0] = c * a0r - s * a1r;  ai[r0] = c * a0i - s * a1i;
        ar[r1] = s * a0r + c * a1r;  ai[r1] = s * a0i + c * a1i;
      }
    }
  }
}

// CNOT: amplitudes with control-bit pc == 1 get target-bit pt flipped.
__device__ __forceinline__ void cnot_gate(float ar[4], float ai[4], int pc, int pt, int lane)
{
  if (pc >= 2 && pt >= 2) {
    const int m = 1 << (pt - 2);
    const bool ctrl = ((lane >> (pc - 2)) & 1) != 0;
#pragma unroll
    for (int r = 0; r < 4; ++r) {
      float br = __shfl_xor(ar[r], m, 64);
      float bi = __shfl_xor(ai[r], m, 64);
      ar[r] = ctrl ? br : ar[r];
      ai[r] = ctrl ? bi : ai[r];
    }
  } else if (pc >= 2) {              // target intra-lane
    const bool ctrl = ((lane >> (pc - 2)) & 1) != 0;
    const int step = 1 << pt;
#pragma unroll
    for (int r0 = 0; r0 < 4; ++r0) {
      if (r0 & step) continue;
      const int r1 = r0 | step;
      float t0 = ctrl ? ar[r1] : ar[r0];
      float t1 = ctrl ? ar[r0] : ar[r1];
      ar[r0] = t0; ar[r1] = t1;
      t0 = ctrl ? ai[r1] : ai[r0];
      t1 = ctrl ? ai[r0] : ai[r1];
      ai[r0] = t0; ai[r1] = t1;
    }
  } else if (pt >= 2) {              // control is a register bit, target is a lane bit
    const int m = 1 << (pt - 2);
#pragma unroll
    for (int r = 0; r < 4; ++r) {
      if (r & (1 << pc)) {           // control==1 amps swap across lanes (symmetric)
        ar[r] = __shfl_xor(ar[r], m, 64);
        ai[r] = __shfl_xor(ai[r], m, 64);
      }
    }
  } else {                           // both bits intra-lane
#pragma unroll
    for (int r0 = 0; r0 < 4; ++r0) {
      if ((r0 & (1 << pt)) == 0 && (r0 & (1 << pc))) {
        const int r1 = r0 | (1 << pt);
        float t = ar[r0]; ar[r0] = ar[r1]; ar[r1] = t;
        t = ai[r0]; ai[r0] = ai[r1]; ai[r1] = t;
      }
    }
  }
}

// One "half" of the circuit: per-qubit RX,RY (angles 0..15) then 3 x [ring CNOT + per-qubit RY] (16..39)
__device__ __forceinline__ void apply_half(float ar[4], float ai[4],
                                           const float2* __restrict__ csb, int lane)
{
  int idx = 0;
#pragma unroll
  for (int j = 0; j < 8; ++j) {
    const float2 crx = csb[idx];
    const float2 cry = csb[idx + 1];
    idx += 2;
    sq_gate(ar, ai, 7 - j, crx.x, crx.y, true,  lane);
    sq_gate(ar, ai, 7 - j, cry.x, cry.y, false, lane);
  }
#pragma unroll
  for (int l = 0; l < 3; ++l) {
#pragma unroll
    for (int j = 0; j < 8; ++j) {
      const int pc = 7 - j;
      const int pt = (j < 7) ? (6 - j) : 7;
      cnot_gate(ar, ai, pc, pt, lane);
    }
#pragma unroll
    for (int j = 0; j < 8; ++j) {
      const float2 cry = csb[idx++];
      sq_gate(ar, ai, 7 - j, cry.x, cry.y, false, lane);
    }
  }
}

__device__ __forceinline__ float expect(const float ar[4], const float ai[4], int lane, bool zall)
{
  float loc;
  if (!zall) {                       // Z on wire 0 = amplitude bit 7 = lane bit 5
    float p = 0.f;
#pragma unroll
    for (int r = 0; r < 4; ++r) p += ar[r] * ar[r] + ai[r] * ai[r];
    loc = ((lane >> 5) & 1) ? -p : p;
  } else {                           // Z on all wires: parity of all amplitude bits
    const int pl = __popc(lane) & 1;
    loc = 0.f;
#pragma unroll
    for (int r = 0; r < 4; ++r) {
      const int pr = (r == 1 || r == 2) ? 1 : 0;
      const float p = ar[r] * ar[r] + ai[r] * ai[r];
      loc += ((pl ^ pr) ? -p : p);
    }
  }
  return wave_sum(loc);
}

__global__ __launch_bounds__(256) void qsal_circuits(
    const float* __restrict__ x,    // [B,S,40]
    const float* __restrict__ pQ,   // [S,40]
    const float* __restrict__ pK,   // [S,40]
    const float* __restrict__ pV,   // [S,40]
    float* __restrict__ Qo, float* __restrict__ Ko, float* __restrict__ Vo) // [B*S]
{
  __shared__ float2 cs[4][160];     // per-wave (cos,sin) of angle/2: [0..39]=x, then wQ,wK,wV
  const int tid  = threadIdx.x;
  const int wid  = tid >> 6;
  const int lane = tid & 63;
  const int gw   = blockIdx.x * 4 + wid;   // b*64 + s
  const int b    = gw >> 6;
  const int s    = gw & 63;

  const float* xa = x + (size_t)(b * SEQd + s) * DF;
#pragma unroll
  for (int t0 = 0; t0 < 3; ++t0) {
    const int t = lane + t0 * 64;
    if (t < 160) {
      float ang;
      if      (t < 40)  ang = xa[t];
      else if (t < 80)  ang = pQ[s * DF + (t - 40)];
      else if (t < 120) ang = pK[s * DF + (t - 80)];
      else              ang = pV[s * DF + (t - 120)];
      float sn, c;
      __sincosf(ang * 0.5f, &sn, &c);
      cs[wid][t] = make_float2(c, sn);
    }
  }
  __syncthreads();

  // |0...0>
  float ar[4], ai[4];
#pragma unroll
  for (int r = 0; r < 4; ++r) { ar[r] = 0.f; ai[r] = 0.f; }
  ar[0] = (lane == 0) ? 1.f : 0.f;

  // encoding half (shared by Q,K,V)
  apply_half(ar, ai, &cs[wid][0], lane);

  float er[4], ei[4];
#pragma unroll
  for (int r = 0; r < 4; ++r) { er[r] = ar[r]; ei[r] = ai[r]; }

  for (int vv = 0; vv < 3; ++vv) {
#pragma unroll
    for (int r = 0; r < 4; ++r) { ar[r] = er[r]; ai[r] = ei[r]; }
    apply_half(ar, ai, &cs[wid][40 + 40 * vv], lane);
    const float e = expect(ar, ai, lane, vv == 2);
    if (lane == 0) {
      float* outp = (vv == 0) ? Qo : ((vv == 1) ? Ko : Vo);
      outp[gw] = e;
    }
  }
}

__global__ __launch_bounds__(256) void qsal_attn(
    const float* __restrict__ x,
    const float* __restrict__ Qv,
    const float* __restrict__ Kv,
    const float* __restrict__ Vv,
    float* __restrict__ out)
{
  const int tid  = threadIdx.x;
  const int wid  = tid >> 6;
  const int lane = tid & 63;                 // m
  const int bi   = blockIdx.x * 4 + wid;     // b*64 + i
  const int b    = bi >> 6;

  const float q = Qv[bi];
  const float k = Kv[b * 64 + lane];
  const float v = Vv[b * 64 + lane];
  const float d = q - k;
  float e  = __expf(-d * d);
  float ev = e * v;
#pragma unroll
  for (int m = 1; m < 64; m <<= 1) {
    e  += __shfl_xor(e,  m, 64);
    ev += __shfl_xor(ev, m, 64);
  }
  const float att = ev / e;

  const size_t row = (size_t)bi * DF;
  if (lane < DF) out[row + lane] = x[row + lane] + att;
}

extern "C" void kernel_launch(void* const* d_in, const int* in_sizes, int n_in,
                              void* d_out, int out_size, void* d_ws, size_t ws_size,
                              hipStream_t stream) {
  const float* x  = (const float*)d_in[0];
  const float* pQ = (const float*)d_in[1];
  const float* pK = (const float*)d_in[2];
  const float* pV = (const float*)d_in[3];
  float* out = (float*)d_out;

  float* Qv = (float*)d_ws;                 // [B*S]
  float* Kv = Qv + BATCHd * SEQd;
  float* Vv = Kv + BATCHd * SEQd;

  const int nwaves = BATCHd * SEQd;         // 16384
  qsal_circuits<<<dim3(nwaves / 4), dim3(256), 0, stream>>>(x, pQ, pK, pV, Qv, Kv, Vv);
  qsal_attn<<<dim3(nwaves / 4), dim3(256), 0, stream>>>(x, Qv, Kv, Vv, out);
}

// Round 2
// 110.745 us; speedup vs baseline: 2.4019x; 2.4019x over previous
//
#include <hip/hip_runtime.h>

#define SEQd 64
#define BATCHd 256
#define DF 40

typedef int v2i __attribute__((ext_vector_type(2)));

__device__ __forceinline__ int lane_id() { return threadIdx.x & 63; }

#if __has_builtin(__builtin_amdgcn_permlane32_swap)
#define HAVE_PL32 1
#endif
#if __has_builtin(__builtin_amdgcn_permlane16_swap)
#define HAVE_PL16 1
#endif

// ---------------------------------------------------------------------------
// Cross-lane exchange: returns value of this register at lane (lane ^ LM).
// LM 1,2,3,7,15 -> DPP (VALU pipe). 16/32/48 -> permlane*_swap (VALU pipe),
// combined polarity-independently via x^y^v (one of ret.x/ret.y is self, the
// other the partner -> XOR recovers the partner exactly). Other LM<32 ->
// ds_swizzle BitMode. LM with bit5 + low bits -> ds_bpermute.
// ---------------------------------------------------------------------------
template<int LM>
__device__ __forceinline__ float xch(float v) {
  if constexpr (LM == 0) {
    return v;
  } else if constexpr (LM == 1 || LM == 2 || LM == 3 || LM == 7 || LM == 15) {
    constexpr int ctrl = (LM == 1) ? 0xB1 : (LM == 2) ? 0x4E : (LM == 3) ? 0x1B
                       : (LM == 7) ? 0x141 : 0x140;
    return __int_as_float(__builtin_amdgcn_mov_dpp(__float_as_int(v), ctrl, 0xF, 0xF, true));
  }
#ifdef HAVE_PL16
  else if constexpr (LM == 16) {
    const int vi = __float_as_int(v);
    v2i r = __builtin_amdgcn_permlane16_swap(vi, vi, false, false);
    return __int_as_float(r.x ^ r.y ^ vi);
  }
#endif
#ifdef HAVE_PL32
  else if constexpr (LM == 32) {
    const int vi = __float_as_int(v);
    v2i r = __builtin_amdgcn_permlane32_swap(vi, vi, false, false);
    return __int_as_float(r.x ^ r.y ^ vi);
  }
  else if constexpr (LM == 48) {
    return xch<16>(xch<32>(v));
  }
#endif
  else if constexpr (LM < 32) {
    return __int_as_float(__builtin_amdgcn_ds_swizzle(__float_as_int(v), (LM << 10) | 0x1F));
  } else {
    return __int_as_float(__builtin_amdgcn_ds_bpermute((lane_id() ^ LM) << 2, __float_as_int(v)));
  }
}

// state: 256 amplitudes; phys index p = lane*4 + k (k = register 0..3)
struct St { float r[4]; float i[4]; };

// RY gate on a relabeled qubit. Partner slot = (lane^LM, k^RM).
// bit(qubit value) = popc(lane&SL)^popc(k&SR). new = c*A + (bit? s:-s)*B
template<int LM, int RM, int SL, int SR>
__device__ __forceinline__ void ry_gate(St& st, float2 cs) {
  const int lane = lane_id();
  float br[4], bi[4];
#pragma unroll
  for (int k = 0; k < 4; ++k) {
    br[k] = xch<LM>(st.r[k ^ RM]);
    bi[k] = xch<LM>(st.i[k ^ RM]);
  }
  float t0;
  if constexpr (SL != 0) t0 = (__popc(lane & SL) & 1) ? cs.y : -cs.y;
  else                   t0 = -cs.y;
#pragma unroll
  for (int k = 0; k < 4; ++k) {
    const float tk = ((__builtin_popcount(k & SR) & 1) ? -t0 : t0);
    st.r[k] = cs.x * st.r[k] + tk * br[k];
    st.i[k] = cs.x * st.i[k] + tk * bi[k];
  }
}

// Fused U = RY(ty)*RX(tx); coef q=(a,b,c2,d)=(cy*cx, sy*sx, sy*cx, cy*sx).
// sigma=+1 for bit=0, -1 for bit=1:
//   Ar' = a*Ar - s*b*Ai - s*c2*Br + d*Bi ; Ai' = a*Ai + s*b*Ar - s*c2*Bi - d*Br
template<int LM, int RM, int SL, int SR>
__device__ __forceinline__ void su2_gate(St& st, float4 q) {
  const int lane = lane_id();
  float br[4], bi[4];
#pragma unroll
  for (int k = 0; k < 4; ++k) {
    br[k] = xch<LM>(st.r[k ^ RM]);
    bi[k] = xch<LM>(st.i[k ^ RM]);
  }
  float sb, sc;
  if constexpr (SL != 0) {
    const bool p = (__popc(lane & SL) & 1) != 0;
    sb = p ? -q.y : q.y;
    sc = p ? -q.z : q.z;
  } else { sb = q.y; sc = q.z; }
#pragma unroll
  for (int k = 0; k < 4; ++k) {
    const bool pk = (__builtin_popcount(k & SR) & 1) != 0;
    const float fb = pk ? -sb : sb;
    const float fc = pk ? -sc : sc;
    const float nr = q.x * st.r[k] - fb * st.i[k] - fc * br[k] + q.w * bi[k];
    const float ni = q.x * st.i[k] + fb * st.r[k] - fc * bi[k] - q.w * br[k];
    st.r[k] = nr; st.i[k] = ni;
  }
}

// 3 x [ring CNOT (free: GF(2) relabeling) + 8 RY]. Masks/sign-rows are the
// compile-time G_l columns / F_l rows (hand-derived, F*G=I verified per layer).
__device__ __forceinline__ void apply_layers(St& st, const float* tabh) {
  const float4* Lc = (const float4*)(tabh + 32);
  {
    const float4 a = Lc[0], b = Lc[1], c = Lc[2], d = Lc[3];
    ry_gate<48,0,0x1F,3>(st, make_float2(a.x, a.y));
    ry_gate<24,0,0x30,0>(st, make_float2(a.z, a.w));
    ry_gate<12,0,0x38,0>(st, make_float2(b.x, b.y));
    ry_gate< 6,0,0x3C,0>(st, make_float2(b.z, b.w));
    ry_gate< 3,0,0x3E,0>(st, make_float2(c.x, c.y));
    ry_gate< 1,2,0x3F,0>(st, make_float2(c.z, c.w));
    ry_gate< 0,3,0x3F,2>(st, make_float2(d.x, d.y));
    ry_gate<48,1,0x3F,3>(st, make_float2(d.z, d.w));
  }
  {
    const float4 a = Lc[4], b = Lc[5], c = Lc[6], d = Lc[7];
    ry_gate<40,0,0x35,1>(st, make_float2(a.x, a.y));
    ry_gate<20,0,0x2F,3>(st, make_float2(a.z, a.w));
    ry_gate<10,0,0x17,3>(st, make_float2(b.x, b.y));
    ry_gate< 5,0,0x2B,3>(st, make_float2(b.z, b.w));
    ry_gate< 2,2,0x15,3>(st, make_float2(c.x, c.y));
    ry_gate< 1,1,0x2A,3>(st, make_float2(c.z, c.w));
    ry_gate<48,2,0x15,1>(st, make_float2(d.x, d.y));
    ry_gate<24,1,0x2A,2>(st, make_float2(d.z, d.w));
  }
  {
    const float4 a = Lc[8], b = Lc[9], c = Lc[10], d = Lc[11];
    ry_gate<60,0,0x13,0>(st, make_float2(a.x, a.y));
    ry_gate<30,0,0x1A,2>(st, make_float2(a.z, a.w));
    ry_gate<15,0,0x0D,1>(st, make_float2(b.x, b.y));
    ry_gate< 7,2,0x26,2>(st, make_float2(b.z, b.w));
    ry_gate< 3,3,0x33,1>(st, make_float2(c.x, c.y));
    ry_gate<49,3,0x19,2>(st, make_float2(c.z, c.w));
    ry_gate<40,3,0x0C,3>(st, make_float2(d.x, d.y));
    ry_gate<36,1,0x26,1>(st, make_float2(d.z, d.w));
  }
}

// initial fused RX*RY on all 8 wires (variational halves; G = I)
__device__ __forceinline__ void apply_initial(St& st, const float* tabh) {
  const float4* F = (const float4*)tabh;
  su2_gate<32,0,0x20,0>(st, F[0]);
  su2_gate<16,0,0x10,0>(st, F[1]);
  su2_gate< 8,0,0x08,0>(st, F[2]);
  su2_gate< 4,0,0x04,0>(st, F[3]);
  su2_gate< 2,0,0x02,0>(st, F[4]);
  su2_gate< 1,0,0x01,0>(st, F[5]);
  su2_gate< 0,2,0x00,2>(st, F[6]);
  su2_gate< 0,1,0x00,1>(st, F[7]);
}

// Encoding half starts from |0..0>: state after initial rotations is the
// product state amp[p] = prod_j u_j[bit_j(p)], u_j = (a+ib, c2-id). Zero DS.
__device__ __forceinline__ void product_init(St& st, const float* tabh) {
  const int lane = lane_id();
  const float4* F = (const float4*)tabh;
  float cr = 1.f, ci = 0.f;
#pragma unroll
  for (int j = 0; j < 6; ++j) {
    const float4 f = F[j];
    const bool bit = ((lane >> (5 - j)) & 1) != 0;
    const float ur = bit ? f.z : f.x;
    const float ui = bit ? -f.w : f.y;
    const float nr = cr * ur - ci * ui;
    const float ni = cr * ui + ci * ur;
    cr = nr; ci = ni;
  }
  const float4 f6 = F[6], f7 = F[7];
#pragma unroll
  for (int k = 0; k < 4; ++k) {
    const bool b6 = (k & 2) != 0;
    const bool b7 = (k & 1) != 0;
    const float ar = b6 ? f6.z : f6.x, ai = b6 ? -f6.w : f6.y;
    const float br2 = b7 ? f7.z : f7.x, bi2 = b7 ? -f7.w : f7.y;
    const float tr = ar * br2 - ai * bi2;
    const float ti = ar * bi2 + ai * br2;
    st.r[k] = cr * tr - ci * ti;
    st.i[k] = cr * ti + ci * tr;
  }
}

// snapshot write resets relabeling to identity: value at slot p goes to F3*p.
// pad every 32 slots by one float2 to spread banks on the linear re-read.
__device__ __forceinline__ int pad_idx(int slot) { return slot + (slot >> 5); }

__device__ __forceinline__ void snap_write(const St& st, float2* snap) {
  const int lane = lane_id();
  int tgt = 0;                       // F3 columns for phys bits 2..7
  if (lane & 1)  tgt ^= 0xAC;
  if (lane & 2)  tgt ^= 0xD9;
  if (lane & 4)  tgt ^= 0x33;
  if (lane & 8)  tgt ^= 0x66;
  if (lane & 16) tgt ^= 0xCC;
  if (lane & 32) tgt ^= 0x19;
  const int rc[4] = {0, 0x2B, 0x56, 0x7D};   // F3 cols for reg bits 0,1
#pragma unroll
  for (int k = 0; k < 4; ++k)
    snap[pad_idx(tgt ^ rc[k])] = make_float2(st.r[k], st.i[k]);
}

__device__ __forceinline__ void snap_read(St& st, const float2* snap) {
  const int lane = lane_id();
#pragma unroll
  for (int k = 0; k < 4; ++k) {
    const float2 v = snap[pad_idx(4 * lane + k)];
    st.r[k] = v.x; st.i[k] = v.y;
  }
}

// <Z...> after a half: sign = parity(lane & smask) (reg part of both
// observables' F3-rows is 0). Z0: row7(F3)=0x4C -> 0x13; Zall: 0x88 -> 0x22.
__device__ __forceinline__ float expect_obs(const St& st, int smask) {
  const int lane = lane_id();
  float p = 0.f;
#pragma unroll
  for (int k = 0; k < 4; ++k) p += st.r[k] * st.r[k] + st.i[k] * st.i[k];
  float v = (__popc(lane & smask) & 1) ? -p : p;
  v += xch<1>(v);  v += xch<2>(v);  v += xch<4>(v);
  v += xch<8>(v);  v += xch<16>(v); v += xch<32>(v);
  return v;
}

// per-(s,half) variational coefficient tables: 80 floats = 8*float4 + 24*float2
__global__ __launch_bounds__(256) void prep_var(
    const float* __restrict__ pQ, const float* __restrict__ pK,
    const float* __restrict__ pV, float* __restrict__ vtab)
{
  const int t = blockIdx.x * 256 + threadIdx.x;   // 0 .. 192*32-1
  if (t >= SEQd * 3 * 32) return;
  const int slot = t & 31;
  const int sh = t >> 5;                          // s*3 + h
  const int h = sh % 3, sp = sh / 3;
  const float* w = ((h == 0) ? pQ : (h == 1) ? pK : pV) + sp * DF;
  float* o = vtab + sh * 80;
  if (slot < 8) {
    float cx, sx, cy, sy;
    __sincosf(w[2 * slot]     * 0.5f, &sx, &cx);
    __sincosf(w[2 * slot + 1] * 0.5f, &sy, &cy);
    ((float4*)o)[slot] = make_float4(cy * cx, sy * sx, sy * cx, cy * sx);
  } else {
    float sn, cn;
    __sincosf(w[16 + (slot - 8)] * 0.5f, &sn, &cn);
    ((float2*)(o + 32))[slot - 8] = make_float2(cn, sn);
  }
}

__global__ __launch_bounds__(256) void qsal_circuits(
    const float* __restrict__ x, const float* __restrict__ vtab,
    float* __restrict__ Qo, float* __restrict__ Ko, float* __restrict__ Vo)
{
  __shared__ __align__(16) float tab[4][320];   // per wave: enc, Q, K, V coefs
  __shared__ float2 snap[4][264];               // per wave padded snapshot
  const int tid = threadIdx.x, wid = tid >> 6, lane = tid & 63;
  const int gw = blockIdx.x * 4 + wid;          // b*64 + s
  const int ss = gw & 63;
  const int su = __builtin_amdgcn_readfirstlane(ss);

  // encoding coefs: sincos of this token's 40 angles
  const float* xa = x + (size_t)gw * DF;
  if (lane < DF) {
    float sn, cn;
    __sincosf(xa[lane] * 0.5f, &sn, &cn);
    int o;
    if (lane < 16) o = (lane >> 1) * 4 + (lane & 1) * 2;  // (cx,sx | cy,sy)
    else           o = 32 + 2 * (lane - 16);
    tab[wid][o] = cn; tab[wid][o + 1] = sn;
  }
  // copy this position's 3 variational tables (240 floats) from global
  {
    const float4* vsrc = (const float4*)(vtab + su * 240);
    if (lane < 60) ((float4*)&tab[wid][80])[lane] = vsrc[lane];
  }
  __syncthreads();
  if (lane < 8) {   // fold (cx,sx,cy,sy) -> (a,b,c2,d) for encoding fused gates
    const float4 f = ((const float4*)tab[wid])[lane];
    ((float4*)tab[wid])[lane] = make_float4(f.z * f.x, f.w * f.y, f.w * f.x, f.z * f.y);
  }
  __syncthreads();

  St st;
  product_init(st, tab[wid]);
  apply_layers(st, tab[wid]);
  snap_write(st, snap[wid]);
  __syncthreads();

  for (int h = 0; h < 3; ++h) {
    St v;
    snap_read(v, snap[wid]);
    const float* th = tab[wid] + 80 * (h + 1);
    apply_initial(v, th);
    apply_layers(v, th);
    const float e = expect_obs(v, (h == 2) ? 0x22 : 0x13);
    if (lane == 0) ((h == 0) ? Qo : (h == 1) ? Ko : Vo)[gw] = e;
  }
}

__global__ __launch_bounds__(256) void qsal_attn(
    const float* __restrict__ x,
    const float* __restrict__ Qv,
    const float* __restrict__ Kv,
    const float* __restrict__ Vv,
    float* __restrict__ out)
{
  const int tid  = threadIdx.x;
  const int wid  = tid >> 6;
  const int lane = tid & 63;                 // m
  const int bi   = blockIdx.x * 4 + wid;     // b*64 + i
  const int b    = bi >> 6;

  const float q = Qv[bi];
  const float k = Kv[b * 64 + lane];
  const float v = Vv[b * 64 + lane];
  const float d = q - k;
  float e  = __expf(-d * d);
  float ev = e * v;
#pragma unroll
  for (int m = 1; m < 64; m <<= 1) {
    e  += __shfl_xor(e,  m, 64);
    ev += __shfl_xor(ev, m, 64);
  }
  const float att = ev / e;

  const size_t row = (size_t)bi * DF;
  if (lane < DF) out[row + lane] = x[row + lane] + att;
}

extern "C" void kernel_launch(void* const* d_in, const int* in_sizes, int n_in,
                              void* d_out, int out_size, void* d_ws, size_t ws_size,
                              hipStream_t stream) {
  const float* x  = (const float*)d_in[0];
  const float* pQ = (const float*)d_in[1];
  const float* pK = (const float*)d_in[2];
  const float* pV = (const float*)d_in[3];
  float* out = (float*)d_out;

  float* Qv   = (float*)d_ws;                    // [16384]
  float* Kv   = Qv + BATCHd * SEQd;
  float* Vv   = Kv + BATCHd * SEQd;
  float* vtab = Vv + BATCHd * SEQd;              // [192*80]

  prep_var<<<dim3(24), dim3(256), 0, stream>>>(pQ, pK, pV, vtab);
  const int nwaves = BATCHd * SEQd;              // 16384
  qsal_circuits<<<dim3(nwaves / 4), dim3(256), 0, stream>>>(x, vtab, Qv, Kv, Vv);
  qsal_attn<<<dim3(nwaves / 4), dim3(256), 0, stream>>>(x, Qv, Kv, Vv, out);
}

// Round 3
// 98.729 us; speedup vs baseline: 2.6942x; 1.1217x over previous
//
#include <hip/hip_runtime.h>

#define SEQd 64
#define BATCHd 256
#define DF 40

typedef float f2 __attribute__((ext_vector_type(2)));

__device__ __forceinline__ int lane_id() { return threadIdx.x & 63; }

// ---------------------------------------------------------------------------
// Cross-lane exchange of one 32-bit value with lane (lane ^ LM).
// {1,2,3,7,15} -> DPP (VALU). Other LM<32 -> ds_swizzle. LM>=32 -> ds_bpermute.
// DS-pipe ops are hidden under the saturated VALU pipe.
// ---------------------------------------------------------------------------
template<int LM>
__device__ __forceinline__ float xch1(float v) {
  if constexpr (LM == 0) {
    return v;
  } else if constexpr (LM == 1 || LM == 2 || LM == 3 || LM == 7 || LM == 15) {
    constexpr int ctrl = (LM == 1) ? 0xB1 : (LM == 2) ? 0x4E : (LM == 3) ? 0x1B
                       : (LM == 7) ? 0x141 : 0x140;
    return __int_as_float(__builtin_amdgcn_mov_dpp(__float_as_int(v), ctrl, 0xF, 0xF, true));
  } else if constexpr (LM < 32) {
    return __int_as_float(__builtin_amdgcn_ds_swizzle(__float_as_int(v), (LM << 10) | 0x1F));
  } else {
    return __int_as_float(__builtin_amdgcn_ds_bpermute((lane_id() ^ LM) << 2, __float_as_int(v)));
  }
}

template<int LM>
__device__ __forceinline__ f2 xch2(f2 v) {
  if constexpr (LM == 0) return v;
  f2 r;
  r.x = xch1<LM>(v.x);
  r.y = xch1<LM>(v.y);
  return r;
}

// (-y, x) : multiply complex pair by structure needed for RX mixing
__device__ __forceinline__ f2 jrot(f2 v) {
  f2 r;
  r.x = -v.y;
  r.y = v.x;
  return r;
}

// state: 256 amplitudes; phys slot p = lane*4 + k; a[k] = (re, im) packed
struct St { f2 a[4]; };

// RY on relabeled qubit. Partner slot = (lane^LM, k^RM).
// bit = popc(lane&SL)^popc(k&SR). new = c*A + (bit? s:-s)*B  (packed re/im)
template<int LM, int RM, int SL, int SR>
__device__ __forceinline__ void ry_gate(St& st, float c, float s) {
  f2 b[4];
#pragma unroll
  for (int k = 0; k < 4; ++k) b[k] = xch2<LM>(st.a[k ^ RM]);
  float t0;
  if constexpr (SL != 0) t0 = (__popc(lane_id() & SL) & 1) ? s : -s;
  else                   t0 = -s;
#pragma unroll
  for (int k = 0; k < 4; ++k) {
    const float tk = (__builtin_popcount(k & SR) & 1) ? -t0 : t0;
    st.a[k] = c * st.a[k] + tk * b[k];
  }
}

// Fused U = RY(ty)*RX(tx); q=(a,b,c2,d)=(cy*cx, sy*sx, sy*cx, cy*sx).
// n = qx*A - fc*B + fb*J(A) - qw*J(B), J(v)=(-v.y, v.x); fb,fc sign-flip with bit.
template<int LM, int RM, int SL, int SR>
__device__ __forceinline__ void su2_gate(St& st, float4 q) {
  f2 b[4];
#pragma unroll
  for (int k = 0; k < 4; ++k) b[k] = xch2<LM>(st.a[k ^ RM]);
  float sb, sc;
  if constexpr (SL != 0) {
    const bool p = (__popc(lane_id() & SL) & 1) != 0;
    sb = p ? -q.y : q.y;
    sc = p ? -q.z : q.z;
  } else { sb = q.y; sc = q.z; }
#pragma unroll
  for (int k = 0; k < 4; ++k) {
    const bool pk = (__builtin_popcount(k & SR) & 1) != 0;
    const float fb = pk ? -sb : sb;
    const float fc = pk ? -sc : sc;
    const f2 A = st.a[k], B = b[k];
    st.a[k] = q.x * A - fc * B + fb * jrot(A) - q.w * jrot(B);
  }
}

// 3 x [ring CNOT (free GF(2) relabeling) + 8 RY]; compile-time mask schedule
// (hand-derived, F*G=I verified per layer; unchanged from the passing round).
__device__ __forceinline__ void apply_layers(St& st, const float* tabh) {
  const float4* Lc = (const float4*)(tabh + 32);
  {
    const float4 a = Lc[0], b = Lc[1], c = Lc[2], d = Lc[3];
    ry_gate<48,0,0x1F,3>(st, a.x, a.y);
    ry_gate<24,0,0x30,0>(st, a.z, a.w);
    ry_gate<12,0,0x38,0>(st, b.x, b.y);
    ry_gate< 6,0,0x3C,0>(st, b.z, b.w);
    ry_gate< 3,0,0x3E,0>(st, c.x, c.y);
    ry_gate< 1,2,0x3F,0>(st, c.z, c.w);
    ry_gate< 0,3,0x3F,2>(st, d.x, d.y);
    ry_gate<48,1,0x3F,3>(st, d.z, d.w);
  }
  {
    const float4 a = Lc[4], b = Lc[5], c = Lc[6], d = Lc[7];
    ry_gate<40,0,0x35,1>(st, a.x, a.y);
    ry_gate<20,0,0x2F,3>(st, a.z, a.w);
    ry_gate<10,0,0x17,3>(st, b.x, b.y);
    ry_gate< 5,0,0x2B,3>(st, b.z, b.w);
    ry_gate< 2,2,0x15,3>(st, c.x, c.y);
    ry_gate< 1,1,0x2A,3>(st, c.z, c.w);
    ry_gate<48,2,0x15,1>(st, d.x, d.y);
    ry_gate<24,1,0x2A,2>(st, d.z, d.w);
  }
  {
    const float4 a = Lc[8], b = Lc[9], c = Lc[10], d = Lc[11];
    ry_gate<60,0,0x13,0>(st, a.x, a.y);
    ry_gate<30,0,0x1A,2>(st, a.z, a.w);
    ry_gate<15,0,0x0D,1>(st, b.x, b.y);
    ry_gate< 7,2,0x26,2>(st, b.z, b.w);
    ry_gate< 3,3,0x33,1>(st, c.x, c.y);
    ry_gate<49,3,0x19,2>(st, c.z, c.w);
    ry_gate<40,3,0x0C,3>(st, d.x, d.y);
    ry_gate<36,1,0x26,1>(st, d.z, d.w);
  }
}

// initial fused RX*RY on all 8 wires (variational halves; G = I)
__device__ __forceinline__ void apply_initial(St& st, const float* tabh) {
  const float4* F = (const float4*)tabh;
  su2_gate<32,0,0x20,0>(st, F[0]);
  su2_gate<16,0,0x10,0>(st, F[1]);
  su2_gate< 8,0,0x08,0>(st, F[2]);
  su2_gate< 4,0,0x04,0>(st, F[3]);
  su2_gate< 2,0,0x02,0>(st, F[4]);
  su2_gate< 1,0,0x01,0>(st, F[5]);
  su2_gate< 0,2,0x00,2>(st, F[6]);
  su2_gate< 0,1,0x00,1>(st, F[7]);
}

// Encoding half: |0..0> through initial rotations is a product state. Zero DS.
__device__ __forceinline__ void product_init(St& st, const float* tabh) {
  const int lane = lane_id();
  const float4* F = (const float4*)tabh;
  float cr = 1.f, ci = 0.f;
#pragma unroll
  for (int j = 0; j < 6; ++j) {
    const float4 f = F[j];
    const bool bit = ((lane >> (5 - j)) & 1) != 0;
    const float ur = bit ? f.z : f.x;
    const float ui = bit ? -f.w : f.y;
    const float nr = cr * ur - ci * ui;
    const float ni = cr * ui + ci * ur;
    cr = nr; ci = ni;
  }
  const float4 f6 = F[6], f7 = F[7];
#pragma unroll
  for (int k = 0; k < 4; ++k) {
    const bool b6 = (k & 2) != 0;
    const bool b7 = (k & 1) != 0;
    const float ar = b6 ? f6.z : f6.x, ai = b6 ? -f6.w : f6.y;
    const float br2 = b7 ? f7.z : f7.x, bi2 = b7 ? -f7.w : f7.y;
    const float tr = ar * br2 - ai * bi2;
    const float ti = ar * bi2 + ai * br2;
    st.a[k].x = cr * tr - ci * ti;
    st.a[k].y = cr * ti + ci * tr;
  }
}

// snapshot write resets relabeling to identity: value at slot p goes to F3*p.
__device__ __forceinline__ int pad_idx(int slot) { return slot + (slot >> 5); }

__device__ __forceinline__ void snap_write(const St& st, f2* snap) {
  const int lane = lane_id();
  int tgt = 0;                       // F3 columns for phys bits 2..7
  if (lane & 1)  tgt ^= 0xAC;
  if (lane & 2)  tgt ^= 0xD9;
  if (lane & 4)  tgt ^= 0x33;
  if (lane & 8)  tgt ^= 0x66;
  if (lane & 16) tgt ^= 0xCC;
  if (lane & 32) tgt ^= 0x19;
  const int rc[4] = {0, 0x2B, 0x56, 0x7D};   // F3 cols for reg bits 0,1
#pragma unroll
  for (int k = 0; k < 4; ++k)
    snap[pad_idx(tgt ^ rc[k])] = st.a[k];
}

__device__ __forceinline__ void snap_read(St& st, const f2* snap) {
  const int lane = lane_id();
#pragma unroll
  for (int k = 0; k < 4; ++k)
    st.a[k] = snap[pad_idx(4 * lane + k)];
}

// <Z...>: sign = parity(lane & smask). Z0 -> 0x13; Zall -> 0x22 (F3 rows).
__device__ __forceinline__ float expect_obs(const St& st, int smask) {
  f2 acc = st.a[0] * st.a[0];
#pragma unroll
  for (int k = 1; k < 4; ++k) acc += st.a[k] * st.a[k];
  float p = acc.x + acc.y;
  float v = (__popc(lane_id() & smask) & 1) ? -p : p;
  v += xch1<1>(v);  v += xch1<2>(v);  v += xch1<4>(v);
  v += xch1<8>(v);  v += xch1<16>(v); v += xch1<32>(v);
  return v;
}

// per-(s,half) variational coefficient tables: 80 floats = 8*float4 + 24*float2
__global__ __launch_bounds__(256) void prep_var(
    const float* __restrict__ pQ, const float* __restrict__ pK,
    const float* __restrict__ pV, float* __restrict__ vtab)
{
  const int t = blockIdx.x * 256 + threadIdx.x;   // 0 .. 192*32-1
  if (t >= SEQd * 3 * 32) return;
  const int slot = t & 31;
  const int sh = t >> 5;                          // s*3 + h
  const int h = sh % 3, sp = sh / 3;
  const float* w = ((h == 0) ? pQ : (h == 1) ? pK : pV) + sp * DF;
  float* o = vtab + sh * 80;
  if (slot < 8) {
    float cx, sx, cy, sy;
    __sincosf(w[2 * slot]     * 0.5f, &sx, &cx);
    __sincosf(w[2 * slot + 1] * 0.5f, &sy, &cy);
    ((float4*)o)[slot] = make_float4(cy * cx, sy * sx, sy * cx, cy * sx);
  } else {
    float sn, cn;
    __sincosf(w[16 + (slot - 8)] * 0.5f, &sn, &cn);
    ((float2*)(o + 32))[slot - 8] = make_float2(cn, sn);
  }
}

__global__ __launch_bounds__(256) void qsal_circuits(
    const float* __restrict__ x, const float* __restrict__ vtab,
    float* __restrict__ Qo, float* __restrict__ Ko, float* __restrict__ Vo)
{
  __shared__ __align__(16) float tab[4][320];   // per wave: enc, Q, K, V coefs
  __shared__ __align__(8) f2 snap[4][264];      // per wave padded snapshot
  const int tid = threadIdx.x, wid = tid >> 6, lane = tid & 63;
  const int gw = blockIdx.x * 4 + wid;          // b*64 + s
  const int ss = gw & 63;
  const int su = __builtin_amdgcn_readfirstlane(ss);

  // encoding coefs: sincos of this token's 40 angles
  const float* xa = x + (size_t)gw * DF;
  if (lane < DF) {
    float sn, cn;
    __sincosf(xa[lane] * 0.5f, &sn, &cn);
    int o;
    if (lane < 16) o = (lane >> 1) * 4 + (lane & 1) * 2;  // (cx,sx | cy,sy)
    else           o = 32 + 2 * (lane - 16);
    tab[wid][o] = cn; tab[wid][o + 1] = sn;
  }
  // copy this position's 3 variational tables (240 floats) from global
  {
    const float4* vsrc = (const float4*)(vtab + su * 240);
    if (lane < 60) ((float4*)&tab[wid][80])[lane] = vsrc[lane];
  }
  __syncthreads();
  if (lane < 8) {   // fold (cx,sx,cy,sy) -> (a,b,c2,d) for encoding fused gates
    const float4 f = ((const float4*)tab[wid])[lane];
    ((float4*)tab[wid])[lane] = make_float4(f.z * f.x, f.w * f.y, f.w * f.x, f.z * f.y);
  }
  __syncthreads();

  St st;
  product_init(st, tab[wid]);
  apply_layers(st, tab[wid]);
  snap_write(st, snap[wid]);
  __syncthreads();

  for (int h = 0; h < 3; ++h) {
    St v;
    snap_read(v, snap[wid]);
    const float* th = tab[wid] + 80 * (h + 1);
    apply_initial(v, th);
    apply_layers(v, th);
    const float e = expect_obs(v, (h == 2) ? 0x22 : 0x13);
    if (lane == 0) ((h == 0) ? Qo : (h == 1) ? Ko : Vo)[gw] = e;
  }
}

__global__ __launch_bounds__(256) void qsal_attn(
    const float* __restrict__ x,
    const float* __restrict__ Qv,
    const float* __restrict__ Kv,
    const float* __restrict__ Vv,
    float* __restrict__ out)
{
  const int tid  = threadIdx.x;
  const int wid  = tid >> 6;
  const int lane = tid & 63;                 // m
  const int bi   = blockIdx.x * 4 + wid;     // b*64 + i
  const int b    = bi >> 6;

  const float q = Qv[bi];
  const float k = Kv[b * 64 + lane];
  const float v = Vv[b * 64 + lane];
  const float d = q - k;
  float e  = __expf(-d * d);
  float ev = e * v;
#pragma unroll
  for (int m = 1; m < 64; m <<= 1) {
    e  += __shfl_xor(e,  m, 64);
    ev += __shfl_xor(ev, m, 64);
  }
  const float att = ev / e;

  const size_t row = (size_t)bi * DF;
  if (lane < DF) out[row + lane] = x[row + lane] + att;
}

extern "C" void kernel_launch(void* const* d_in, const int* in_sizes, int n_in,
                              void* d_out, int out_size, void* d_ws, size_t ws_size,
                              hipStream_t stream) {
  const float* x  = (const float*)d_in[0];
  const float* pQ = (const float*)d_in[1];
  const float* pK = (const float*)d_in[2];
  const float* pV = (const float*)d_in[3];
  float* out = (float*)d_out;

  float* Qv   = (float*)d_ws;                    // [16384]
  float* Kv   = Qv + BATCHd * SEQd;
  float* Vv   = Kv + BATCHd * SEQd;
  float* vtab = Vv + BATCHd * SEQd;              // [192*80]

  prep_var<<<dim3(24), dim3(256), 0, stream>>>(pQ, pK, pV, vtab);
  const int nwaves = BATCHd * SEQd;              // 16384
  qsal_circuits<<<dim3(nwaves / 4), dim3(256), 0, stream>>>(x, vtab, Qv, Kv, Vv);
  qsal_attn<<<dim3(nwaves / 4), dim3(256), 0, stream>>>(x, Qv, Kv, Vv, out);
}

// Round 5
// 82.935 us; speedup vs baseline: 3.2073x; 1.1904x over previous
//
#include <hip/hip_runtime.h>

#define SEQd 64
#define BATCHd 256
#define DF 40

typedef float f2 __attribute__((ext_vector_type(2)));
typedef __fp16 h2v __attribute__((ext_vector_type(2)));

// ---------------------------------------------------------------------------
// 8-qubit statevector, 16 lanes per circuit, 16 amps (f2) per lane.
// Physical amp index p (8 bits) = (lane_local << 4) | k.
// All gate masks below are the SAME 8-bit constants as the proven 4-amp
// kernel ((LM_old<<2)|RM_old), re-split as LM=M>>4 (lane), RM=M&15 (reg).
// GF(2) relabeling schedule + sign rows cross-validated against it.
// ---------------------------------------------------------------------------

__device__ __forceinline__ int lane_id() { return threadIdx.x & 63; }

template<int LM>
__device__ __forceinline__ float xch1(float v) {
  if constexpr (LM == 0) {
    return v;
  } else if constexpr (LM == 1 || LM == 2 || LM == 3 || LM == 7 || LM == 15) {
    constexpr int ctrl = (LM == 1) ? 0xB1 : (LM == 2) ? 0x4E : (LM == 3) ? 0x1B
                       : (LM == 7) ? 0x141 : 0x140;
    return __int_as_float(__builtin_amdgcn_mov_dpp(__float_as_int(v), ctrl, 0xF, 0xF, true));
  } else {
    return __int_as_float(__builtin_amdgcn_ds_swizzle(__float_as_int(v), (LM << 10) | 0x1F));
  }
}

template<int LM>
__device__ __forceinline__ f2 xch2(f2 v) {
  if constexpr (LM == 0) return v;
  f2 r; r.x = xch1<LM>(v.x); r.y = xch1<LM>(v.y); return r;
}

__device__ __forceinline__ f2 jrot(f2 v) { f2 r; r.x = -v.y; r.y = v.x; return r; }

// RY gate; M = pairing mask (LM|RM), SM = sign row (SL|SR).
// bit = popc(lam&SL)^popc(k&SR); new = c*A + (bit? s:-s)*partner
template<int M, int SM>
__device__ __forceinline__ void ry16(f2* a, f2 cs, int lam) {
  constexpr int LM = M >> 4, RM = M & 15, SL = SM >> 4, SR = SM & 15;
  const float c = cs.x, s = cs.y;
  float t0;
  if constexpr (SL != 0) t0 = (__popc(lam & SL) & 1) ? s : -s;
  else                   t0 = -s;
#pragma unroll
  for (int k = 0; k < 16; ++k) {
    const int kp = k ^ RM;
    if (kp < k) continue;
    if (kp == k) {
      const f2 b = xch2<LM>(a[k]);
      const float tk = (__builtin_popcount(k & SR) & 1) ? -t0 : t0;
      a[k] = c * a[k] + tk * b;
    } else {
      const f2 b0 = xch2<LM>(a[kp]);
      const f2 b1 = xch2<LM>(a[k]);
      const float tk  = (__builtin_popcount(k  & SR) & 1) ? -t0 : t0;
      const float tkp = (__builtin_popcount(kp & SR) & 1) ? -t0 : t0;
      a[k]  = c * a[k]  + tk  * b0;
      a[kp] = c * a[kp] + tkp * b1;
    }
  }
}

// Fused U = RY(ty)*RX(tx); q=(a,b,c2,d)=(cy*cx, sy*sx, sy*cx, cy*sx).
template<int M, int SM>
__device__ __forceinline__ void su2_16(f2* a, float4 q, int lam) {
  constexpr int LM = M >> 4, RM = M & 15, SL = SM >> 4, SR = SM & 15;
  float sb, sc;
  if constexpr (SL != 0) {
    const bool p = (__popc(lam & SL) & 1) != 0;
    sb = p ? -q.y : q.y; sc = p ? -q.z : q.z;
  } else { sb = q.y; sc = q.z; }
#pragma unroll
  for (int k = 0; k < 16; ++k) {
    const int kp = k ^ RM;
    if (kp < k) continue;
    if (kp == k) {
      const f2 B = xch2<LM>(a[k]);
      const bool pk = (__builtin_popcount(k & SR) & 1) != 0;
      const float fb = pk ? -sb : sb, fc = pk ? -sc : sc;
      const f2 A = a[k];
      a[k] = q.x * A - fc * B + fb * jrot(A) - q.w * jrot(B);
    } else {
      const f2 B0 = xch2<LM>(a[kp]);
      const f2 B1 = xch2<LM>(a[k]);
      const bool pk  = (__builtin_popcount(k  & SR) & 1) != 0;
      const bool pkp = (__builtin_popcount(kp & SR) & 1) != 0;
      const float fb0 = pk  ? -sb : sb, fc0 = pk  ? -sc : sc;
      const float fb1 = pkp ? -sb : sb, fc1 = pkp ? -sc : sc;
      const f2 A0 = a[k], A1 = a[kp];
      a[k]  = q.x * A0 - fc0 * B0 + fb0 * jrot(A0) - q.w * jrot(B0);
      a[kp] = q.x * A1 - fc1 * B1 + fb1 * jrot(A1) - q.w * jrot(B1);
    }
  }
}

// 3 x [ring CNOT (free) + 8 RY]; masks/signs = G1..G3 cols / F1..F3 rows.
__device__ __forceinline__ void layers16(f2* a, const float* __restrict__ tabh, int lam) {
  const f2* L = (const f2*)(tabh + 32);
  ry16<0xC0,0x7F>(a, L[0],  lam);
  ry16<0x60,0xC0>(a, L[1],  lam);
  ry16<0x30,0xE0>(a, L[2],  lam);
  ry16<0x18,0xF0>(a, L[3],  lam);
  ry16<0x0C,0xF8>(a, L[4],  lam);
  ry16<0x06,0xFC>(a, L[5],  lam);
  ry16<0x03,0xFE>(a, L[6],  lam);
  ry16<0xC1,0xFF>(a, L[7],  lam);
  ry16<0xA0,0xD5>(a, L[8],  lam);
  ry16<0x50,0xBF>(a, L[9],  lam);
  ry16<0x28,0x5F>(a, L[10], lam);
  ry16<0x14,0xAF>(a, L[11], lam);
  ry16<0x0A,0x57>(a, L[12], lam);
  ry16<0x05,0xAB>(a, L[13], lam);
  ry16<0xC2,0x55>(a, L[14], lam);
  ry16<0x61,0xAA>(a, L[15], lam);
  ry16<0xF0,0x4C>(a, L[16], lam);
  ry16<0x78,0x6A>(a, L[17], lam);
  ry16<0x3C,0x35>(a, L[18], lam);
  ry16<0x1E,0x9A>(a, L[19], lam);
  ry16<0x0F,0xCD>(a, L[20], lam);
  ry16<0xC7,0x66>(a, L[21], lam);
  ry16<0xA3,0x33>(a, L[22], lam);
  ry16<0x91,0x99>(a, L[23], lam);
}

// initial fused RX*RY on all 8 wires (variational halves; F0 = I)
__device__ __forceinline__ void initial16(f2* a, const float4* __restrict__ F, int lam) {
  su2_16<0x80,0x80>(a, F[0], lam);
  su2_16<0x40,0x40>(a, F[1], lam);
  su2_16<0x20,0x20>(a, F[2], lam);
  su2_16<0x10,0x10>(a, F[3], lam);
  su2_16<0x08,0x08>(a, F[4], lam);
  su2_16<0x04,0x04>(a, F[5], lam);
  su2_16<0x02,0x02>(a, F[6], lam);
  su2_16<0x01,0x01>(a, F[7], lam);
}

// Encoding half from |0..0>: product state, zero exchanges.
// lane bit i -> wire 3-i; k bit0->wire7, bit1->wire6, bit2->wire5, bit3->wire4
__device__ __forceinline__ void pinit16(f2* a, const float4* __restrict__ F, int lam) {
  f2 c; c.x = 1.f; c.y = 0.f;
#pragma unroll
  for (int i = 0; i < 4; ++i) {
    const float4 f = F[3 - i];
    const bool bit = ((lam >> i) & 1) != 0;
    const float ur = bit ? f.z : f.x;
    const float ui = bit ? -f.w : f.y;
    f2 n; n.x = c.x * ur - c.y * ui; n.y = c.x * ui + c.y * ur;
    c = n;
  }
  const float4 f7 = F[7], f6 = F[6], f5 = F[5], f4 = F[4];
  f2 w67[4], w45[4];
#pragma unroll
  for (int j = 0; j < 4; ++j) {
    const bool b7 = (j & 1) != 0, b6 = (j & 2) != 0;
    const float a7r = b7 ? f7.z : f7.x, a7i = b7 ? -f7.w : f7.y;
    const float a6r = b6 ? f6.z : f6.x, a6i = b6 ? -f6.w : f6.y;
    w67[j].x = a6r * a7r - a6i * a7i; w67[j].y = a6r * a7i + a6i * a7r;
    const bool b5 = (j & 1) != 0, b4 = (j & 2) != 0;
    const float a5r = b5 ? f5.z : f5.x, a5i = b5 ? -f5.w : f5.y;
    const float a4r = b4 ? f4.z : f4.x, a4i = b4 ? -f4.w : f4.y;
    w45[j].x = a4r * a5r - a4i * a5i; w45[j].y = a4r * a5i + a4i * a5r;
  }
#pragma unroll
  for (int k = 0; k < 16; ++k) {
    const f2 u = w67[k & 3], w = w45[(k >> 2) & 3];
    f2 t; t.x = u.x * w.x - u.y * w.y; t.y = u.x * w.y + u.y * w.x;
    a[k].x = c.x * t.x - c.y * t.y;
    a[k].y = c.x * t.y + c.y * t.x;
  }
}

__device__ __forceinline__ uint32_t packh(f2 v) {
  h2v h = __builtin_amdgcn_cvt_pkrtz(v.x, v.y);
  return __builtin_bit_cast(uint32_t, h);
}
__device__ __forceinline__ f2 unpackh(uint32_t u) {
  h2v h = __builtin_bit_cast(h2v, u);
  f2 r; r.x = (float)h[0]; r.y = (float)h[1]; return r;
}

// snapshot: value at slot p -> address F3*p (resets relabeling to identity)
__device__ __forceinline__ void snap_write16(const f2* a, uint32_t* sn, int lam) {
  int tgt = 0;                        // F3 columns for lane bits (p4..p7)
  if (lam & 1) tgt ^= 0x33;
  if (lam & 2) tgt ^= 0x66;
  if (lam & 4) tgt ^= 0xCC;
  if (lam & 8) tgt ^= 0x19;
  constexpr int rc[16] = {0x00,0x2B,0x56,0x7D,0xAC,0x87,0xFA,0xD1,
                          0xD9,0xF2,0x8F,0xA4,0x75,0x5E,0x23,0x08};
#pragma unroll
  for (int k = 0; k < 16; ++k) sn[tgt ^ rc[k]] = packh(a[k]);
}

__device__ __forceinline__ void snap_read16(f2* a, const uint32_t* sn, int lam) {
  const uint4* p = (const uint4*)(sn + lam * 16);
#pragma unroll
  for (int q = 0; q < 4; ++q) {
    const uint4 w = p[q];
    a[4*q+0] = unpackh(w.x); a[4*q+1] = unpackh(w.y);
    a[4*q+2] = unpackh(w.z); a[4*q+3] = unpackh(w.w);
  }
}

// <Z...>: Z0 -> SM 0x4C; Zall -> SM 0x88 (F3 rows; validated vs old kernel)
template<int SM>
__device__ __forceinline__ float expect16(const f2* a, int lam) {
  constexpr int SL = SM >> 4, SR = SM & 15;
  float s0 = 0.f, s1 = 0.f;
#pragma unroll
  for (int k = 0; k < 16; ++k) {
    const float p = a[k].x * a[k].x + a[k].y * a[k].y;
    if ((__builtin_popcount(k & SR) & 1) != 0) s1 += p; else s0 += p;
  }
  const float d = s0 - s1;
  float v = (__popc(lam & SL) & 1) ? -d : d;
  v += xch1<1>(v); v += xch1<2>(v); v += xch1<4>(v); v += xch1<8>(v);
  return v;
}

// per-(s,half) variational coefficient tables: 80 floats = 8*float4 + 24*float2
__global__ __launch_bounds__(256) void prep_var(
    const float* __restrict__ pQ, const float* __restrict__ pK,
    const float* __restrict__ pV, float* __restrict__ vtab)
{
  const int t = blockIdx.x * 256 + threadIdx.x;
  if (t >= SEQd * 3 * 32) return;
  const int slot = t & 31;
  const int sh = t >> 5;
  const int h = sh % 3, sp = sh / 3;
  const float* w = ((h == 0) ? pQ : (h == 1) ? pK : pV) + sp * DF;
  float* o = vtab + sh * 80;
  if (slot < 8) {
    float cx, sx, cy, sy;
    __sincosf(w[2 * slot]     * 0.5f, &sx, &cx);
    __sincosf(w[2 * slot + 1] * 0.5f, &sy, &cy);
    ((float4*)o)[slot] = make_float4(cy * cx, sy * sx, sy * cx, cy * sx);
  } else {
    float sn, cn;
    __sincosf(w[16 + (slot - 8)] * 0.5f, &sn, &cn);
    ((float2*)(o + 32))[slot - 8] = make_float2(cn, sn);
  }
}

// Block = 256 threads = 4 waves = 16 circuits, ALL sharing one s
// (var tables block-uniform -> scalar loads from global; enc tabs in LDS).
__global__ __launch_bounds__(256) void qsal_circuits(
    const float* __restrict__ x, const float* __restrict__ vtab,
    float* __restrict__ Qo, float* __restrict__ Ko, float* __restrict__ Vo)
{
  __shared__ __align__(16) float etab[16][80];
  __shared__ __align__(16) uint32_t snap[16][264];   // stride 264 spreads banks
  const int tid  = threadIdx.x;
  const int wid  = tid >> 6, lane = tid & 63, lam = lane & 15;
  const int s     = blockIdx.x & 63;
  const int bbase = (blockIdx.x >> 6) << 4;
  const int ci    = wid * 4 + (lane >> 4);

  // fill enc coef tables: 16 circuits x 40 angles
#pragma unroll
  for (int rep = 0; rep < 3; ++rep) {
    const int aIdx = tid + rep * 256;
    if (aIdx < 640) {
      const int cc = aIdx / 40, idx = aIdx - cc * 40;
      const float ang = x[((size_t)(bbase + cc) * 64 + s) * 40 + idx];
      float sn, cn; __sincosf(ang * 0.5f, &sn, &cn);
      if (idx < 16) {
        const int wire = idx >> 1, isy = idx & 1;
        etab[cc][wire * 4 + isy * 2 + 0] = cn;
        etab[cc][wire * 4 + isy * 2 + 1] = sn;
      } else {
        etab[cc][32 + (idx - 16) * 2 + 0] = cn;
        etab[cc][32 + (idx - 16) * 2 + 1] = sn;
      }
    }
  }
  __syncthreads();
  if (tid < 128) {  // fold (cx,sx,cy,sy) -> (a,b,c2,d)
    const int cc = tid >> 3, wire = tid & 7;
    float4* q = (float4*)etab[cc];
    const float4 f = q[wire];
    q[wire] = make_float4(f.z * f.x, f.w * f.y, f.w * f.x, f.z * f.y);
  }
  __syncthreads();

  f2 a[16];
  pinit16(a, (const float4*)etab[ci], lam);
  layers16(a, etab[ci], lam);
  snap_write16(a, snap[ci], lam);
  __syncthreads();

  const float* vg = vtab + s * 240;   // block-uniform
  float e[3];
#pragma unroll
  for (int h = 0; h < 3; ++h) {
    f2 v[16];
    snap_read16(v, snap[ci], lam);
    const float* th = vg + 80 * h;
    initial16(v, (const float4*)th, lam);
    layers16(v, th, lam);
    e[h] = (h == 2) ? expect16<0x88>(v, lam) : expect16<0x4C>(v, lam);
  }
  if (lam == 0) {
    const int gw = (bbase + ci) * 64 + s;
    Qo[gw] = e[0]; Ko[gw] = e[1]; Vo[gw] = e[2];
  }
}

__global__ __launch_bounds__(256) void qsal_attn(
    const float* __restrict__ x,
    const float* __restrict__ Qv,
    const float* __restrict__ Kv,
    const float* __restrict__ Vv,
    float* __restrict__ out)
{
  const int tid  = threadIdx.x;
  const int wid  = tid >> 6;
  const int lane = tid & 63;                 // m
  const int bi   = blockIdx.x * 4 + wid;     // b*64 + i
  const int b    = bi >> 6;

  const float q = Qv[bi];
  const float k = Kv[b * 64 + lane];
  const float v = Vv[b * 64 + lane];
  const float d = q - k;
  float e  = __expf(-d * d);
  float ev = e * v;
#pragma unroll
  for (int m = 1; m < 64; m <<= 1) {
    e  += __shfl_xor(e,  m, 64);
    ev += __shfl_xor(ev, m, 64);
  }
  const float att = ev / e;

  const size_t row = (size_t)bi * DF;
  if (lane < DF) out[row + lane] = x[row + lane] + att;
}

extern "C" void kernel_launch(void* const* d_in, const int* in_sizes, int n_in,
                              void* d_out, int out_size, void* d_ws, size_t ws_size,
                              hipStream_t stream) {
  const float* x  = (const float*)d_in[0];
  const float* pQ = (const float*)d_in[1];
  const float* pK = (const float*)d_in[2];
  const float* pV = (const float*)d_in[3];
  float* out = (float*)d_out;

  float* Qv   = (float*)d_ws;                    // [16384]
  float* Kv   = Qv + BATCHd * SEQd;
  float* Vv   = Kv + BATCHd * SEQd;
  float* vtab = Vv + BATCHd * SEQd;              // [64*3*80]

  prep_var<<<dim3(24), dim3(256), 0, stream>>>(pQ, pK, pV, vtab);
  qsal_circuits<<<dim3(1024), dim3(256), 0, stream>>>(x, vtab, Qv, Kv, Vv);
  qsal_attn<<<dim3(BATCHd * SEQd / 4), dim3(256), 0, stream>>>(x, Qv, Kv, Vv, out);
}